// Round 10
// baseline (118.480 us; speedup 1.0000x reference)
//
#include <hip/hip_runtime.h>

#define NXROWS 32768
#define NY     4096
#define MCOLS  16
#define BLOCK  256
#define KSPLIT 16
#define KCHUNK (NY / KSPLIT)               // 256
#define NITER  (KCHUNK / 32)               // 8
#define ROWS_PER_BLOCK 256                 // 4 waves x 4 tiles x 16 rows
#define GRIDX  (NXROWS / ROWS_PER_BLOCK)   // 128 -> grid 128x16 = 2048 blocks = 8/CU

#define TPS_C 0.34657359027997264f  // 0.5*ln2: r^2 ln r = TPS_C * sq * log2(sq)

typedef __bf16 bf16x8 __attribute__((ext_vector_type(8)));
typedef short  s16x8  __attribute__((ext_vector_type(8)));
typedef float  f32x4  __attribute__((ext_vector_type(4)));

// ws layout (bytes):
//   [0,      65536)   y4   : 4096 x float4 (-2y0,-2y1,-2y2,|y|^2)
//   [65536, 196608)   cT   : bf16 [16][4096] = TPS_C * coeffs^T
//   [262144, +32MiB)  part : f32 [KSPLIT][NXROWS][MCOLS] (streamed writes)
#define WS_Y4_OFF   0
#define WS_CT_OFF   65536
#define WS_PART_OFF 262144
#define WS_END      (WS_PART_OFF + (size_t)KSPLIT * NXROWS * MCOLS * 4)

static __device__ __forceinline__ unsigned short f2bfu(float f) {
    __bf16 h = (__bf16)f;
    return __builtin_bit_cast(unsigned short, h);
}

// ---- prep: cT (TPS_C-scaled bf16 transposed coeffs) + scaled y4. 144 blocks.
__global__ __launch_bounds__(BLOCK) void rbf_prep3(
    const float* __restrict__ y, const float* __restrict__ coeffs,
    float4* __restrict__ y4, unsigned int* __restrict__ cTw)
{
    const int idx = blockIdx.x * BLOCK + threadIdx.x;
    if (idx < MCOLS * NY / 2) {                   // cT build (u32-packed writes)
        const int m  = idx >> 11;                 // 2048 j-pairs per m
        const int jp = (idx & 2047) * 2;
        const unsigned short u0 = f2bfu(TPS_C * coeffs[(size_t)jp * MCOLS + m]);
        const unsigned short u1 = f2bfu(TPS_C * coeffs[(size_t)(jp + 1) * MCOLS + m]);
        cTw[((size_t)m * NY + jp) >> 1] = (unsigned int)u0 | ((unsigned int)u1 << 16);
    } else {                                      // y4 build (pre-scaled)
        const int j = idx - MCOLS * NY / 2;       // < NY
        const float y0 = y[3 * j], y1 = y[3 * j + 1], y2 = y[3 * j + 2];
        y4[j] = make_float4(-2.f * y0, -2.f * y1, -2.f * y2,
                            y0 * y0 + y1 * y1 + y2 * y2);
    }
}

// ---- main: 4 waves x 4 M-tiles; whole K-chunk staged in LDS, inner loop is
// LDS+VALU only. ys swizzled (+1 float4 per 8) so the 4 q-groups hit distinct
// bank groups; cs rows padded +8 bf16 (2-way aliasing = free).
// A-frag: lane l -> row=l&15, k=(l>>4)*8+e ; B-frag: n=l&15, k=(l>>4)*8+e
// C/D:    lane l -> col=l&15, row=(l>>4)*4+reg   (m89-verified)
__global__ __launch_bounds__(BLOCK, 8) void rbf_mfma5(
    const float* __restrict__ x, const float4* __restrict__ y4,
    const unsigned int* __restrict__ cTw, float* __restrict__ part)
{
    __shared__ float4 ys[KCHUNK + KCHUNK / 8];            // 4.5 KB, swizzled
    __shared__ unsigned short cs[MCOLS][KCHUNK + 8];      // 8.25 KB

    const int tid   = threadIdx.x;
    const int kbase = blockIdx.y * KCHUNK;

    ys[tid + (tid >> 3)] = y4[kbase + tid];               // 1 float4/thread
    {
        unsigned int* csw = reinterpret_cast<unsigned int*>(&cs[0][0]);
        #pragma unroll
        for (int i = tid; i < MCOLS * KCHUNK / 2; i += BLOCK) {
            const int m = i >> 7;                          // 128 u32 per row
            const int c = i & 127;
            csw[m * ((KCHUNK + 8) / 2) + c] = cTw[m * (NY / 2) + kbase / 2 + c];
        }
    }
    __syncthreads();

    const int lane = tid & 63;
    const int wid  = tid >> 6;
    const int n    = lane & 15;
    const int q    = lane >> 4;
    const int rowBase = blockIdx.x * ROWS_PER_BLOCK + wid * 64;

    float sx[4], a0[4], a1[4], a2[4];
    #pragma unroll
    for (int t = 0; t < 4; ++t) {
        const int r = rowBase + t * 16 + n;
        const float c0 = x[r * 3], c1 = x[r * 3 + 1], c2 = x[r * 3 + 2];
        sx[t] = c0 * c0 + c1 * c1 + c2 * c2;
        a0[t] = c0; a1[t] = c1; a2[t] = c2;   // y4 carries the -2 factor
    }

    // swizzled lane base: idx = ks*32 + q*8 + e  ->  ys[ks*36 + q*9 + e]
    const float4* ysp = ys + q * 9;
    const unsigned short* csp = &cs[n][q * 8];

    f32x4 acc[4];
    #pragma unroll
    for (int t = 0; t < 4; ++t) acc[t] = (f32x4){0.f, 0.f, 0.f, 0.f};

    for (int ks = 0; ks < NITER; ++ks) {
        const s16x8 braw = *reinterpret_cast<const s16x8*>(csp + ks * 32);
        bf16x8 af[4];
        #pragma unroll
        for (int e = 0; e < 8; ++e) {
            const float4 v = ysp[ks * 36 + e];
            #pragma unroll
            for (int t = 0; t < 4; ++t) {
                float s = fmaf(a0[t], v.x,
                          fmaf(a1[t], v.y,
                          fmaf(a2[t], v.z, sx[t] + v.w)));
                s = fmaxf(s, 1e-14f);
                af[t][e] = (__bf16)(s * __log2f(s));
            }
        }
        const bf16x8 bf = __builtin_bit_cast(bf16x8, braw);
        #pragma unroll
        for (int t = 0; t < 4; ++t)
            acc[t] = __builtin_amdgcn_mfma_f32_16x16x32_bf16(af[t], bf, acc[t], 0, 0, 0);
    }

    float* plane = part + (size_t)blockIdx.y * NXROWS * MCOLS;
    #pragma unroll
    for (int t = 0; t < 4; ++t) {
        float* o = plane + (size_t)(rowBase + t * 16 + q * 4) * MCOLS + n;
        #pragma unroll
        for (int r = 0; r < 4; ++r) o[(size_t)r * MCOLS] = acc[t][r];
    }
}

// ---- reduce KSPLIT planes + polynomial tail; full overwrite of out.
__global__ __launch_bounds__(BLOCK) void rbf_reduce(
    const float* __restrict__ part, const float* __restrict__ x,
    const float* __restrict__ shift, const float* __restrict__ scale,
    const float* __restrict__ coeffs, const int* __restrict__ powers,
    int nR, float* __restrict__ out)
{
    const int idx = blockIdx.x * BLOCK + threadIdx.x;
    const int row = idx >> 2, mq = idx & 3;
    f32x4 s = {0.f, 0.f, 0.f, 0.f};
    #pragma unroll
    for (int sp = 0; sp < KSPLIT; ++sp) {
        const f32x4 v = *reinterpret_cast<const f32x4*>(
            part + (size_t)sp * NXROWS * MCOLS + (size_t)row * MCOLS + mq * 4);
        s += v;
    }
    float xh[3];
    #pragma unroll
    for (int d = 0; d < 3; ++d) xh[d] = (x[row * 3 + d] - shift[d]) / scale[d];
    for (int r = 0; r < nR; ++r) {
        float p = 1.0f;
        for (int d = 0; d < 3; ++d) {
            const int pw = powers[r * 3 + d];
            for (int k = 0; k < pw; ++k) p *= xh[d];
        }
        const f32x4 cv = *reinterpret_cast<const f32x4*>(
            coeffs + (size_t)(NY + r) * MCOLS + mq * 4);
        s += p * cv;
    }
    *reinterpret_cast<f32x4*>(out + (size_t)row * MCOLS + mq * 4) = s;
}

// ---- fallback (ws too small; effectively never): pure f32 atomic path.
__global__ __launch_bounds__(BLOCK) void rbf_f32_atomic(
    const float* __restrict__ x, const float* __restrict__ y,
    const float* __restrict__ coeffs, float* __restrict__ out)
{
    const int jbase = blockIdx.y * 512;
    const int row = blockIdx.x * BLOCK + threadIdx.x;
    const float x0 = x[row * 3], x1 = x[row * 3 + 1], x2 = x[row * 3 + 2];
    float acc[MCOLS];
    #pragma unroll
    for (int m = 0; m < MCOLS; ++m) acc[m] = 0.f;
    const float4* c4 = reinterpret_cast<const float4*>(coeffs) + (size_t)jbase * 4;
    for (int j = 0; j < 512; ++j) {
        const float dx = x0 - y[(jbase + j) * 3 + 0];
        const float dy = x1 - y[(jbase + j) * 3 + 1];
        const float dz = x2 - y[(jbase + j) * 3 + 2];
        const float sq = fmaxf(dx * dx + dy * dy + dz * dz, 1e-14f);
        const float t = TPS_C * sq * __log2f(sq);
        #pragma unroll
        for (int g = 0; g < 4; ++g) {
            const float4 cv = c4[j * 4 + g];
            acc[g * 4 + 0] += t * cv.x; acc[g * 4 + 1] += t * cv.y;
            acc[g * 4 + 2] += t * cv.z; acc[g * 4 + 3] += t * cv.w;
        }
    }
    #pragma unroll
    for (int m = 0; m < MCOLS; ++m)
        atomicAdd(&out[(size_t)row * MCOLS + m], acc[m]);
}

__global__ __launch_bounds__(BLOCK) void rbf_poly_atomic(
    const float* __restrict__ x, const float* __restrict__ shift,
    const float* __restrict__ scale, const float* __restrict__ coeffs,
    const int* __restrict__ powers, int nR, float* __restrict__ out)
{
    const int idx = blockIdx.x * BLOCK + threadIdx.x;
    const int row = idx >> 2, mq = idx & 3;
    float xh[3];
    #pragma unroll
    for (int d = 0; d < 3; ++d) xh[d] = (x[row * 3 + d] - shift[d]) / scale[d];
    f32x4 s = {0.f, 0.f, 0.f, 0.f};
    for (int r = 0; r < nR; ++r) {
        float p = 1.0f;
        for (int d = 0; d < 3; ++d) {
            const int pw = powers[r * 3 + d];
            for (int k = 0; k < pw; ++k) p *= xh[d];
        }
        const f32x4 cv = *reinterpret_cast<const f32x4*>(
            coeffs + (size_t)(NY + r) * MCOLS + mq * 4);
        s += p * cv;
    }
    float* o = out + (size_t)row * MCOLS + mq * 4;
    atomicAdd(o + 0, s.x); atomicAdd(o + 1, s.y);
    atomicAdd(o + 2, s.z); atomicAdd(o + 3, s.w);
}

extern "C" void kernel_launch(void* const* d_in, const int* in_sizes, int n_in,
                              void* d_out, int out_size, void* d_ws, size_t ws_size,
                              hipStream_t stream) {
    const float* x      = (const float*)d_in[0];
    const float* y      = (const float*)d_in[1];
    const float* shift  = (const float*)d_in[2];
    const float* scale  = (const float*)d_in[3];
    const float* coeffs = (const float*)d_in[4];
    const int*   powers = (const int*)d_in[5];
    const int    nR     = in_sizes[5] / 3;
    float* out = (float*)d_out;

    if (ws_size >= WS_END) {
        char* ws = (char*)d_ws;
        float4*       y4   = (float4*)(ws + WS_Y4_OFF);
        unsigned int* cTw  = (unsigned int*)(ws + WS_CT_OFF);
        float*        part = (float*)(ws + WS_PART_OFF);
        rbf_prep3<<<(MCOLS * NY / 2 + NY) / BLOCK, BLOCK, 0, stream>>>(
            y, coeffs, y4, cTw);
        rbf_mfma5<<<dim3(GRIDX, KSPLIT), BLOCK, 0, stream>>>(x, y4, cTw, part);
        rbf_reduce<<<NXROWS * 4 / BLOCK, BLOCK, 0, stream>>>(
            part, x, shift, scale, coeffs, powers, nR, out);
    } else {
        hipMemsetAsync(d_out, 0, (size_t)out_size * sizeof(float), stream);
        rbf_f32_atomic<<<dim3(NXROWS / BLOCK, NY / 512), BLOCK, 0, stream>>>(
            x, y, coeffs, out);
        rbf_poly_atomic<<<NXROWS * 4 / BLOCK, BLOCK, 0, stream>>>(
            x, shift, scale, coeffs, powers, nR, out);
    }
}

// Round 11
// 112.498 us; speedup vs baseline: 1.0532x; 1.0532x over previous
//
#include <hip/hip_runtime.h>

#define NXROWS 32768
#define NY     4096
#define MCOLS  16
#define BLOCK  256
#define KSPLIT 8
#define KCHUNK (NY / KSPLIT)               // 512
#define NITER  (KCHUNK / 32)               // 16
#define ROWS_PER_BLOCK 256                 // 4 waves x 4 tiles x 16 rows
#define GRIDX  (NXROWS / ROWS_PER_BLOCK)   // 128 -> grid 128x8 = 1024 blocks

#define TPS_C 0.34657359027997264f  // 0.5*ln2: r^2 ln r = TPS_C * sq * log2(sq)

typedef __bf16 bf16x8 __attribute__((ext_vector_type(8)));
typedef short  s16x8  __attribute__((ext_vector_type(8)));
typedef float  f32x4  __attribute__((ext_vector_type(4)));

// ws layout (bytes):
//   [0,      65536)   y4   : 4096 x float4 (-2y0,-2y1,-2y2,|y|^2)
//   [65536, 196608)   cT   : bf16 [16][4096] = TPS_C * coeffs^T
//   [196608,262144)   pad  : absorbs the last-iteration prefetch overrun
//   [262144, +16MiB)  part : f32 [KSPLIT][NXROWS][MCOLS] (streamed writes)
// KSPLIT=8 keeps per-XCD part-write footprint at 2MB (fits 4MB L2 alongside
// y4/cT) -- R10 showed KSPLIT=16 (4MB/XCD) thrashes L2 (FETCH 985KB->14.9MB).
#define WS_Y4_OFF   0
#define WS_CT_OFF   65536
#define WS_PART_OFF 262144
#define WS_END      (WS_PART_OFF + (size_t)KSPLIT * NXROWS * MCOLS * 4)

static __device__ __forceinline__ unsigned short f2bfu(float f) {
    __bf16 h = (__bf16)f;
    return __builtin_bit_cast(unsigned short, h);
}

// ---- prep: cT (TPS_C-scaled bf16 transposed coeffs) + pre-scaled y4.
__global__ __launch_bounds__(BLOCK) void rbf_prep3(
    const float* __restrict__ y, const float* __restrict__ coeffs,
    float4* __restrict__ y4, unsigned int* __restrict__ cTw)
{
    const int idx = blockIdx.x * BLOCK + threadIdx.x;
    if (idx < MCOLS * NY / 2) {                   // cT build (u32-packed writes)
        const int m  = idx >> 11;                 // 2048 j-pairs per m
        const int jp = (idx & 2047) * 2;
        const unsigned short u0 = f2bfu(TPS_C * coeffs[(size_t)jp * MCOLS + m]);
        const unsigned short u1 = f2bfu(TPS_C * coeffs[(size_t)(jp + 1) * MCOLS + m]);
        cTw[((size_t)m * NY + jp) >> 1] = (unsigned int)u0 | ((unsigned int)u1 << 16);
    } else {                                      // y4 build (pre-scaled)
        const int j = idx - MCOLS * NY / 2;       // < NY
        const float y0 = y[3 * j], y1 = y[3 * j + 1], y2 = y[3 * j + 2];
        y4[j] = make_float4(-2.f * y0, -2.f * y1, -2.f * y2,
                            y0 * y0 + y1 * y1 + y2 * y2);
    }
}

// ---- main: 4 waves x 4 M-tiles (64 rows/wave); K in 32-steps via MFMA.
// Cross-K software pipeline: K-step ks+1's 9 loads are issued BEFORE
// computing ks, pinned with sched_barrier(0) so the compiler can't sink
// loads back to their use-site (what defeated R7's ping-pong).
// A-frag: lane l -> row=l&15, k=(l>>4)*8+e ; B-frag: n=l&15, k=(l>>4)*8+e
// C/D:    lane l -> col=l&15, row=(l>>4)*4+reg   (m89-verified)
__global__ __launch_bounds__(BLOCK, 4) void rbf_mfma6(
    const float* __restrict__ x, const float4* __restrict__ y4,
    const unsigned short* __restrict__ cT, float* __restrict__ part)
{
    const int lane = threadIdx.x & 63;
    const int wid  = threadIdx.x >> 6;
    const int n    = lane & 15;
    const int q    = lane >> 4;
    const int rowBase = blockIdx.x * ROWS_PER_BLOCK + wid * 64;
    const int kbase = blockIdx.y * KCHUNK;

    float sx[4], a0[4], a1[4], a2[4];
    #pragma unroll
    for (int t = 0; t < 4; ++t) {
        const int r = rowBase + t * 16 + n;
        const float c0 = x[r * 3], c1 = x[r * 3 + 1], c2 = x[r * 3 + 2];
        sx[t] = c0 * c0 + c1 * c1 + c2 * c2;
        a0[t] = c0; a1[t] = c1; a2[t] = c2;   // y4 carries the -2 factor
    }

    const float4* yb = y4 + kbase + q * 8;
    const unsigned short* cb = cT + (size_t)n * NY + kbase + q * 8;

    f32x4 acc[4];
    #pragma unroll
    for (int t = 0; t < 4; ++t) acc[t] = (f32x4){0.f, 0.f, 0.f, 0.f};

    float4 yA[8], yB[8];
    s16x8 bA, bB;

#define LOADT(YV, BR, KS) do {                                           \
    _Pragma("unroll")                                                    \
    for (int e = 0; e < 8; ++e) YV[e] = yb[(KS) * 32 + e];               \
    BR = *reinterpret_cast<const s16x8*>(cb + (KS) * 32);                \
} while (0)

#define CONSUME(YV, BR) do {                                             \
    bf16x8 af[4];                                                        \
    _Pragma("unroll")                                                    \
    for (int e = 0; e < 8; ++e) {                                        \
        const float4 v = YV[e];                                          \
        _Pragma("unroll")                                                \
        for (int t = 0; t < 4; ++t) {                                    \
            float s = fmaf(a0[t], v.x,                                   \
                      fmaf(a1[t], v.y,                                   \
                      fmaf(a2[t], v.z, sx[t] + v.w)));                   \
            s = fmaxf(s, 1e-14f);                                        \
            af[t][e] = (__bf16)(s * __log2f(s));                         \
        }                                                                \
    }                                                                    \
    const bf16x8 bf = __builtin_bit_cast(bf16x8, BR);                    \
    _Pragma("unroll")                                                    \
    for (int t = 0; t < 4; ++t)                                          \
        acc[t] = __builtin_amdgcn_mfma_f32_16x16x32_bf16(af[t], bf, acc[t], 0, 0, 0); \
} while (0)

    LOADT(yA, bA, 0);
    for (int ks = 0; ks < NITER; ks += 2) {
        LOADT(yB, bB, ks + 1);                  // prefetch ks+1
        __builtin_amdgcn_sched_barrier(0);      // pin: loads stay above
        CONSUME(yA, bA);
        LOADT(yA, bA, ks + 2);                  // prefetch ks+2 (last one
        __builtin_amdgcn_sched_barrier(0);      //  overruns into ws pad)
        CONSUME(yB, bB);
    }
#undef LOADT
#undef CONSUME

    float* plane = part + (size_t)blockIdx.y * NXROWS * MCOLS;
    #pragma unroll
    for (int t = 0; t < 4; ++t) {
        float* o = plane + (size_t)(rowBase + t * 16 + q * 4) * MCOLS + n;
        #pragma unroll
        for (int r = 0; r < 4; ++r) o[(size_t)r * MCOLS] = acc[t][r];
    }
}

// ---- reduce KSPLIT planes + polynomial tail; full overwrite of out.
__global__ __launch_bounds__(BLOCK) void rbf_reduce(
    const float* __restrict__ part, const float* __restrict__ x,
    const float* __restrict__ shift, const float* __restrict__ scale,
    const float* __restrict__ coeffs, const int* __restrict__ powers,
    int nR, float* __restrict__ out)
{
    const int idx = blockIdx.x * BLOCK + threadIdx.x;
    const int row = idx >> 2, mq = idx & 3;
    f32x4 s = {0.f, 0.f, 0.f, 0.f};
    #pragma unroll
    for (int sp = 0; sp < KSPLIT; ++sp) {
        const f32x4 v = *reinterpret_cast<const f32x4*>(
            part + (size_t)sp * NXROWS * MCOLS + (size_t)row * MCOLS + mq * 4);
        s += v;
    }
    float xh[3];
    #pragma unroll
    for (int d = 0; d < 3; ++d) xh[d] = (x[row * 3 + d] - shift[d]) / scale[d];
    for (int r = 0; r < nR; ++r) {
        float p = 1.0f;
        for (int d = 0; d < 3; ++d) {
            const int pw = powers[r * 3 + d];
            for (int k = 0; k < pw; ++k) p *= xh[d];
        }
        const f32x4 cv = *reinterpret_cast<const f32x4*>(
            coeffs + (size_t)(NY + r) * MCOLS + mq * 4);
        s += p * cv;
    }
    *reinterpret_cast<f32x4*>(out + (size_t)row * MCOLS + mq * 4) = s;
}

// ---- fallback (ws too small; effectively never): pure f32 atomic path.
__global__ __launch_bounds__(BLOCK) void rbf_f32_atomic(
    const float* __restrict__ x, const float* __restrict__ y,
    const float* __restrict__ coeffs, float* __restrict__ out)
{
    const int jbase = blockIdx.y * 512;
    const int row = blockIdx.x * BLOCK + threadIdx.x;
    const float x0 = x[row * 3], x1 = x[row * 3 + 1], x2 = x[row * 3 + 2];
    float acc[MCOLS];
    #pragma unroll
    for (int m = 0; m < MCOLS; ++m) acc[m] = 0.f;
    const float4* c4 = reinterpret_cast<const float4*>(coeffs) + (size_t)jbase * 4;
    for (int j = 0; j < 512; ++j) {
        const float dx = x0 - y[(jbase + j) * 3 + 0];
        const float dy = x1 - y[(jbase + j) * 3 + 1];
        const float dz = x2 - y[(jbase + j) * 3 + 2];
        const float sq = fmaxf(dx * dx + dy * dy + dz * dz, 1e-14f);
        const float t = TPS_C * sq * __log2f(sq);
        #pragma unroll
        for (int g = 0; g < 4; ++g) {
            const float4 cv = c4[j * 4 + g];
            acc[g * 4 + 0] += t * cv.x; acc[g * 4 + 1] += t * cv.y;
            acc[g * 4 + 2] += t * cv.z; acc[g * 4 + 3] += t * cv.w;
        }
    }
    #pragma unroll
    for (int m = 0; m < MCOLS; ++m)
        atomicAdd(&out[(size_t)row * MCOLS + m], acc[m]);
}

__global__ __launch_bounds__(BLOCK) void rbf_poly_atomic(
    const float* __restrict__ x, const float* __restrict__ shift,
    const float* __restrict__ scale, const float* __restrict__ coeffs,
    const int* __restrict__ powers, int nR, float* __restrict__ out)
{
    const int idx = blockIdx.x * BLOCK + threadIdx.x;
    const int row = idx >> 2, mq = idx & 3;
    float xh[3];
    #pragma unroll
    for (int d = 0; d < 3; ++d) xh[d] = (x[row * 3 + d] - shift[d]) / scale[d];
    f32x4 s = {0.f, 0.f, 0.f, 0.f};
    for (int r = 0; r < nR; ++r) {
        float p = 1.0f;
        for (int d = 0; d < 3; ++d) {
            const int pw = powers[r * 3 + d];
            for (int k = 0; k < pw; ++k) p *= xh[d];
        }
        const f32x4 cv = *reinterpret_cast<const f32x4*>(
            coeffs + (size_t)(NY + r) * MCOLS + mq * 4);
        s += p * cv;
    }
    float* o = out + (size_t)row * MCOLS + mq * 4;
    atomicAdd(o + 0, s.x); atomicAdd(o + 1, s.y);
    atomicAdd(o + 2, s.z); atomicAdd(o + 3, s.w);
}

extern "C" void kernel_launch(void* const* d_in, const int* in_sizes, int n_in,
                              void* d_out, int out_size, void* d_ws, size_t ws_size,
                              hipStream_t stream) {
    const float* x      = (const float*)d_in[0];
    const float* y      = (const float*)d_in[1];
    const float* shift  = (const float*)d_in[2];
    const float* scale  = (const float*)d_in[3];
    const float* coeffs = (const float*)d_in[4];
    const int*   powers = (const int*)d_in[5];
    const int    nR     = in_sizes[5] / 3;
    float* out = (float*)d_out;

    if (ws_size >= WS_END) {
        char* ws = (char*)d_ws;
        float4*         y4   = (float4*)(ws + WS_Y4_OFF);
        unsigned short* cT   = (unsigned short*)(ws + WS_CT_OFF);
        unsigned int*   cTw  = (unsigned int*)(ws + WS_CT_OFF);
        float*          part = (float*)(ws + WS_PART_OFF);
        rbf_prep3<<<(MCOLS * NY / 2 + NY) / BLOCK, BLOCK, 0, stream>>>(
            y, coeffs, y4, cTw);
        rbf_mfma6<<<dim3(GRIDX, KSPLIT), BLOCK, 0, stream>>>(x, y4, cT, part);
        rbf_reduce<<<NXROWS * 4 / BLOCK, BLOCK, 0, stream>>>(
            part, x, shift, scale, coeffs, powers, nR, out);
    } else {
        hipMemsetAsync(d_out, 0, (size_t)out_size * sizeof(float), stream);
        rbf_f32_atomic<<<dim3(NXROWS / BLOCK, NY / 512), BLOCK, 0, stream>>>(
            x, y, coeffs, out);
        rbf_poly_atomic<<<NXROWS * 4 / BLOCK, BLOCK, 0, stream>>>(
            x, shift, scale, coeffs, powers, nR, out);
    }
}

// Round 12
// 111.271 us; speedup vs baseline: 1.0648x; 1.0110x over previous
//
#include <hip/hip_runtime.h>

#define NXROWS 32768
#define NY     4096
#define MCOLS  16
#define BLOCK  256
#define KSPLIT 16
#define KCHUNK (NY / KSPLIT)               // 256
#define NITER  (KCHUNK / 32)               // 8
#define ROWS_PER_BLOCK 256                 // 4 waves x 4 tiles x 16 rows
#define GRIDX  (NXROWS / ROWS_PER_BLOCK)   // 128 -> grid 128x16 = 2048 blocks = 8/CU

#define TPS_C 0.34657359027997264f  // 0.5*ln2: r^2 ln r = TPS_C * sq * log2(sq)

typedef __bf16 bf16x8 __attribute__((ext_vector_type(8)));
typedef short  s16x8  __attribute__((ext_vector_type(8)));
typedef float  f32x4  __attribute__((ext_vector_type(4)));

// ws layout (bytes):
//   [0,      65536)   y4   : 4096 x float4 (-2y0,-2y1,-2y2,|y|^2)
//   [65536, 196608)   cT   : bf16 [16][4096] = TPS_C * coeffs^T
//   [196608,262144)   pad  : absorbs the last-iteration prefetch overrun
//   [262144, +16MiB)  part : bf16 [KSPLIT][NXROWS][MCOLS] (streamed writes)
// bf16 partials keep KSPLIT=16's write footprint at 2MB/XCD -- R9's proven
// clean geometry (R10's f32@16 = 4MB/XCD thrashed L2: FETCH 985KB->14.9MB).
#define WS_Y4_OFF   0
#define WS_CT_OFF   65536
#define WS_PART_OFF 262144
#define WS_END      (WS_PART_OFF + (size_t)KSPLIT * NXROWS * MCOLS * 2)

static __device__ __forceinline__ unsigned short f2bfu(float f) {
    __bf16 h = (__bf16)f;
    return __builtin_bit_cast(unsigned short, h);
}
static __device__ __forceinline__ float bfu2f(unsigned short u) {
    const unsigned int w = (unsigned int)u << 16;
    return __builtin_bit_cast(float, w);
}

// ---- prep: cT (TPS_C-scaled bf16 transposed coeffs) + pre-scaled y4.
__global__ __launch_bounds__(BLOCK) void rbf_prep3(
    const float* __restrict__ y, const float* __restrict__ coeffs,
    float4* __restrict__ y4, unsigned int* __restrict__ cTw)
{
    const int idx = blockIdx.x * BLOCK + threadIdx.x;
    if (idx < MCOLS * NY / 2) {                   // cT build (u32-packed writes)
        const int m  = idx >> 11;                 // 2048 j-pairs per m
        const int jp = (idx & 2047) * 2;
        const unsigned short u0 = f2bfu(TPS_C * coeffs[(size_t)jp * MCOLS + m]);
        const unsigned short u1 = f2bfu(TPS_C * coeffs[(size_t)(jp + 1) * MCOLS + m]);
        cTw[((size_t)m * NY + jp) >> 1] = (unsigned int)u0 | ((unsigned int)u1 << 16);
    } else {                                      // y4 build (pre-scaled)
        const int j = idx - MCOLS * NY / 2;       // < NY
        const float y0 = y[3 * j], y1 = y[3 * j + 1], y2 = y[3 * j + 2];
        y4[j] = make_float4(-2.f * y0, -2.f * y1, -2.f * y2,
                            y0 * y0 + y1 * y1 + y2 * y2);
    }
}

// ---- main: 4 waves x 4 M-tiles (64 rows/wave); K in 32-steps via MFMA.
// Body identical to R11 (VGPR 64 -> 8 waves/SIMD resident); only KSPLIT and
// the partial dtype changed. Cross-K pipeline pinned with sched_barrier(0).
// A-frag: lane l -> row=l&15, k=(l>>4)*8+e ; B-frag: n=l&15, k=(l>>4)*8+e
// C/D:    lane l -> col=l&15, row=(l>>4)*4+reg   (m89-verified)
__global__ __launch_bounds__(BLOCK, 4) void rbf_mfma7(
    const float* __restrict__ x, const float4* __restrict__ y4,
    const unsigned short* __restrict__ cT, unsigned short* __restrict__ part)
{
    const int lane = threadIdx.x & 63;
    const int wid  = threadIdx.x >> 6;
    const int n    = lane & 15;
    const int q    = lane >> 4;
    const int rowBase = blockIdx.x * ROWS_PER_BLOCK + wid * 64;
    const int kbase = blockIdx.y * KCHUNK;

    float sx[4], a0[4], a1[4], a2[4];
    #pragma unroll
    for (int t = 0; t < 4; ++t) {
        const int r = rowBase + t * 16 + n;
        const float c0 = x[r * 3], c1 = x[r * 3 + 1], c2 = x[r * 3 + 2];
        sx[t] = c0 * c0 + c1 * c1 + c2 * c2;
        a0[t] = c0; a1[t] = c1; a2[t] = c2;   // y4 carries the -2 factor
    }

    const float4* yb = y4 + kbase + q * 8;
    const unsigned short* cb = cT + (size_t)n * NY + kbase + q * 8;

    f32x4 acc[4];
    #pragma unroll
    for (int t = 0; t < 4; ++t) acc[t] = (f32x4){0.f, 0.f, 0.f, 0.f};

    float4 yA[8], yB[8];
    s16x8 bA, bB;

#define LOADT(YV, BR, KS) do {                                           \
    _Pragma("unroll")                                                    \
    for (int e = 0; e < 8; ++e) YV[e] = yb[(KS) * 32 + e];               \
    BR = *reinterpret_cast<const s16x8*>(cb + (KS) * 32);                \
} while (0)

#define CONSUME(YV, BR) do {                                             \
    bf16x8 af[4];                                                        \
    _Pragma("unroll")                                                    \
    for (int e = 0; e < 8; ++e) {                                        \
        const float4 v = YV[e];                                          \
        _Pragma("unroll")                                                \
        for (int t = 0; t < 4; ++t) {                                    \
            float s = fmaf(a0[t], v.x,                                   \
                      fmaf(a1[t], v.y,                                   \
                      fmaf(a2[t], v.z, sx[t] + v.w)));                   \
            s = fmaxf(s, 1e-14f);                                        \
            af[t][e] = (__bf16)(s * __log2f(s));                         \
        }                                                                \
    }                                                                    \
    const bf16x8 bf = __builtin_bit_cast(bf16x8, BR);                    \
    _Pragma("unroll")                                                    \
    for (int t = 0; t < 4; ++t)                                          \
        acc[t] = __builtin_amdgcn_mfma_f32_16x16x32_bf16(af[t], bf, acc[t], 0, 0, 0); \
} while (0)

    LOADT(yA, bA, 0);
    for (int ks = 0; ks < NITER; ks += 2) {
        LOADT(yB, bB, ks + 1);                  // prefetch ks+1
        __builtin_amdgcn_sched_barrier(0);      // pin: loads stay above
        CONSUME(yA, bA);
        LOADT(yA, bA, ks + 2);                  // prefetch ks+2 (last one
        __builtin_amdgcn_sched_barrier(0);      //  overruns into ws pad)
        CONSUME(yB, bB);
    }
#undef LOADT
#undef CONSUME

    unsigned short* plane = part + (size_t)blockIdx.y * NXROWS * MCOLS;
    #pragma unroll
    for (int t = 0; t < 4; ++t) {
        unsigned short* o = plane + (size_t)(rowBase + t * 16 + q * 4) * MCOLS + n;
        #pragma unroll
        for (int r = 0; r < 4; ++r) o[(size_t)r * MCOLS] = f2bfu(acc[t][r]);
    }
}

// ---- reduce KSPLIT bf16 planes + polynomial tail; full overwrite of out.
__global__ __launch_bounds__(BLOCK) void rbf_reduce7(
    const unsigned short* __restrict__ part, const float* __restrict__ x,
    const float* __restrict__ shift, const float* __restrict__ scale,
    const float* __restrict__ coeffs, const int* __restrict__ powers,
    int nR, float* __restrict__ out)
{
    const int idx = blockIdx.x * BLOCK + threadIdx.x;
    const int row = idx >> 2, mq = idx & 3;
    f32x4 s = {0.f, 0.f, 0.f, 0.f};
    #pragma unroll
    for (int sp = 0; sp < KSPLIT; ++sp) {
        const ushort4 v = *reinterpret_cast<const ushort4*>(
            part + (size_t)sp * NXROWS * MCOLS + (size_t)row * MCOLS + mq * 4);
        s.x += bfu2f(v.x); s.y += bfu2f(v.y);
        s.z += bfu2f(v.z); s.w += bfu2f(v.w);
    }
    float xh[3];
    #pragma unroll
    for (int d = 0; d < 3; ++d) xh[d] = (x[row * 3 + d] - shift[d]) / scale[d];
    for (int r = 0; r < nR; ++r) {
        float p = 1.0f;
        for (int d = 0; d < 3; ++d) {
            const int pw = powers[r * 3 + d];
            for (int k = 0; k < pw; ++k) p *= xh[d];
        }
        const f32x4 cv = *reinterpret_cast<const f32x4*>(
            coeffs + (size_t)(NY + r) * MCOLS + mq * 4);
        s += p * cv;
    }
    *reinterpret_cast<f32x4*>(out + (size_t)row * MCOLS + mq * 4) = s;
}

// ---- fallback (ws too small; effectively never): pure f32 atomic path.
__global__ __launch_bounds__(BLOCK) void rbf_f32_atomic(
    const float* __restrict__ x, const float* __restrict__ y,
    const float* __restrict__ coeffs, float* __restrict__ out)
{
    const int jbase = blockIdx.y * 512;
    const int row = blockIdx.x * BLOCK + threadIdx.x;
    const float x0 = x[row * 3], x1 = x[row * 3 + 1], x2 = x[row * 3 + 2];
    float acc[MCOLS];
    #pragma unroll
    for (int m = 0; m < MCOLS; ++m) acc[m] = 0.f;
    const float4* c4 = reinterpret_cast<const float4*>(coeffs) + (size_t)jbase * 4;
    for (int j = 0; j < 512; ++j) {
        const float dx = x0 - y[(jbase + j) * 3 + 0];
        const float dy = x1 - y[(jbase + j) * 3 + 1];
        const float dz = x2 - y[(jbase + j) * 3 + 2];
        const float sq = fmaxf(dx * dx + dy * dy + dz * dz, 1e-14f);
        const float t = TPS_C * sq * __log2f(sq);
        #pragma unroll
        for (int g = 0; g < 4; ++g) {
            const float4 cv = c4[j * 4 + g];
            acc[g * 4 + 0] += t * cv.x; acc[g * 4 + 1] += t * cv.y;
            acc[g * 4 + 2] += t * cv.z; acc[g * 4 + 3] += t * cv.w;
        }
    }
    #pragma unroll
    for (int m = 0; m < MCOLS; ++m)
        atomicAdd(&out[(size_t)row * MCOLS + m], acc[m]);
}

__global__ __launch_bounds__(BLOCK) void rbf_poly_atomic(
    const float* __restrict__ x, const float* __restrict__ shift,
    const float* __restrict__ scale, const float* __restrict__ coeffs,
    const int* __restrict__ powers, int nR, float* __restrict__ out)
{
    const int idx = blockIdx.x * BLOCK + threadIdx.x;
    const int row = idx >> 2, mq = idx & 3;
    float xh[3];
    #pragma unroll
    for (int d = 0; d < 3; ++d) xh[d] = (x[row * 3 + d] - shift[d]) / scale[d];
    f32x4 s = {0.f, 0.f, 0.f, 0.f};
    for (int r = 0; r < nR; ++r) {
        float p = 1.0f;
        for (int d = 0; d < 3; ++d) {
            const int pw = powers[r * 3 + d];
            for (int k = 0; k < pw; ++k) p *= xh[d];
        }
        const f32x4 cv = *reinterpret_cast<const f32x4*>(
            coeffs + (size_t)(NY + r) * MCOLS + mq * 4);
        s += p * cv;
    }
    float* o = out + (size_t)row * MCOLS + mq * 4;
    atomicAdd(o + 0, s.x); atomicAdd(o + 1, s.y);
    atomicAdd(o + 2, s.z); atomicAdd(o + 3, s.w);
}

extern "C" void kernel_launch(void* const* d_in, const int* in_sizes, int n_in,
                              void* d_out, int out_size, void* d_ws, size_t ws_size,
                              hipStream_t stream) {
    const float* x      = (const float*)d_in[0];
    const float* y      = (const float*)d_in[1];
    const float* shift  = (const float*)d_in[2];
    const float* scale  = (const float*)d_in[3];
    const float* coeffs = (const float*)d_in[4];
    const int*   powers = (const int*)d_in[5];
    const int    nR     = in_sizes[5] / 3;
    float* out = (float*)d_out;

    if (ws_size >= WS_END) {
        char* ws = (char*)d_ws;
        float4*         y4   = (float4*)(ws + WS_Y4_OFF);
        unsigned short* cT   = (unsigned short*)(ws + WS_CT_OFF);
        unsigned int*   cTw  = (unsigned int*)(ws + WS_CT_OFF);
        unsigned short* part = (unsigned short*)(ws + WS_PART_OFF);
        rbf_prep3<<<(MCOLS * NY / 2 + NY) / BLOCK, BLOCK, 0, stream>>>(
            y, coeffs, y4, cTw);
        rbf_mfma7<<<dim3(GRIDX, KSPLIT), BLOCK, 0, stream>>>(x, y4, cT, part);
        rbf_reduce7<<<NXROWS * 4 / BLOCK, BLOCK, 0, stream>>>(
            part, x, shift, scale, coeffs, powers, nR, out);
    } else {
        hipMemsetAsync(d_out, 0, (size_t)out_size * sizeof(float), stream);
        rbf_f32_atomic<<<dim3(NXROWS / BLOCK, NY / 512), BLOCK, 0, stream>>>(
            x, y, coeffs, out);
        rbf_poly_atomic<<<NXROWS * 4 / BLOCK, BLOCK, 0, stream>>>(
            x, shift, scale, coeffs, powers, nR, out);
    }
}